// Round 1
// baseline (1398.892 us; speedup 1.0000x reference)
//
#include <hip/hip_runtime.h>
#include <hip/hip_bf16.h>
#include <math.h>

#define N_SUB 4096
#define N_EDGES 65536
#define N_FULLY (2 * 8 * N_SUB)   // 65536

// workspace layout (float offsets)
#define OFF_DEG   0        // 4096  (deg -> dinv in place)
#define OFF_TX1   4096     // 16384 (4096 x 4)
#define OFF_S2    20480    // 16384 (4096 x 4)  = lhat(Tx1)
#define OFF_LOG   36864    // 4096  logits accumulator
#define OFF_VAL   40960    // 1     value accumulator
#define ZERO_FLOATS 40964  // everything above must start at zero
#define OFF_VIRT  40964    // 8
#define OFF_CONV  40976    // 32768 (4096 x 8)
#define OFF_FULLY 73744    // 65536

__global__ void k_deg(const int* __restrict__ src, float* __restrict__ deg) {
    int e = blockIdx.x * blockDim.x + threadIdx.x;
    if (e < N_EDGES) atomicAdd(&deg[src[e]], 1.0f);
}

__global__ void k_dinv(float* __restrict__ deg) {
    int i = blockIdx.x * blockDim.x + threadIdx.x;
    if (i < N_SUB) {
        float d = deg[i];
        deg[i] = (d > 0.0f) ? (1.0f / sqrtf(d)) : 0.0f;
    }
}

// out[dst] += (-dinv[src]*dinv[dst]) * h[src],  h is [N_SUB,4]
__global__ void k_scatter(const int* __restrict__ src, const int* __restrict__ dst,
                          const float* __restrict__ dinv, const float* __restrict__ h,
                          float* __restrict__ out) {
    int e = blockIdx.x * blockDim.x + threadIdx.x;
    if (e >= N_EDGES) return;
    int s = src[e], d = dst[e];
    float w = -dinv[s] * dinv[d];
    float4 hv = ((const float4*)h)[s];
    atomicAdd(&out[d * 4 + 0], w * hv.x);
    atomicAdd(&out[d * 4 + 1], w * hv.y);
    atomicAdd(&out[d * 4 + 2], w * hv.z);
    atomicAdd(&out[d * 4 + 3], w * hv.w);
}

// conv[n][o] = relu( sum_k Tx0*W0 + Tx1*W1 + (2*S2 - Tx0)*W2 + b ), and virt[8]
__global__ void k_conv(const float* __restrict__ x0, const float* __restrict__ tx1,
                       const float* __restrict__ s2,
                       const float* __restrict__ chebW, const float* __restrict__ chebB,
                       const float* __restrict__ vnrx, const float* __restrict__ vnrW,
                       const float* __restrict__ vnrB, const int* __restrict__ jp,
                       float* __restrict__ conv, float* __restrict__ virt) {
    int n = blockIdx.x * blockDim.x + threadIdx.x;
    if (n < N_SUB) {
        float4 a4 = ((const float4*)x0)[n];
        float4 b4 = ((const float4*)tx1)[n];
        float4 s4 = ((const float4*)s2)[n];
        float a[4] = {a4.x, a4.y, a4.z, a4.w};
        float b[4] = {b4.x, b4.y, b4.z, b4.w};
        float c[4] = {2.f*s4.x - a4.x, 2.f*s4.y - a4.y, 2.f*s4.z - a4.z, 2.f*s4.w - a4.w};
        #pragma unroll
        for (int o = 0; o < 8; o++) {
            float acc = chebB[o];
            #pragma unroll
            for (int k = 0; k < 4; k++) {
                acc += a[k] * chebW[k * 8 + o]
                     + b[k] * chebW[32 + k * 8 + o]
                     + c[k] * chebW[64 + k * 8 + o];
            }
            conv[n * 8 + o] = fmaxf(acc, 0.0f);
        }
    }
    if (blockIdx.x == 0 && threadIdx.x < 8) {
        int j = jp[0];
        int o = threadIdx.x;
        virt[o] = vnrB[o] + vnrx[j * 2 + 0] * vnrW[o] + vnrx[j * 2 + 1] * vnrW[8 + o];
    }
}

// fully[i] = tanh( pre[perm[i]] ); also accumulate value = sum fully[i]*valW[i]
__global__ void k_fully(const int* __restrict__ perm, const float* __restrict__ conv,
                        const float* __restrict__ virt, const float* __restrict__ valW,
                        float* __restrict__ fully, float* __restrict__ vacc) {
    int i = blockIdx.x * blockDim.x + threadIdx.x;
    float vc = 0.0f;
    if (i < N_FULLY) {
        int p = perm[i];
        float v = (p < 8 * N_SUB) ? virt[p & 7] : conv[p - 8 * N_SUB];
        float f = tanhf(v);
        fully[i] = f;
        vc = f * valW[i];
    }
    #pragma unroll
    for (int off = 32; off; off >>= 1) vc += __shfl_down(vc, off, 64);
    if ((threadIdx.x & 63) == 0) atomicAdd(vacc, vc);
}

// logits[m] += sum_i fully[i] * polW[i][m]; grid 1024 blocks x 256 threads.
// block: colBlock = bid&3 (1024 cols), rowChunk = bid>>2 (256 rows)
__global__ __launch_bounds__(256) void k_logits(const float* __restrict__ fully,
                                                const float* __restrict__ polW,
                                                float* __restrict__ logits) {
    __shared__ float xs[256];
    int bid = blockIdx.x;
    int col = (bid & 3) * 1024 + threadIdx.x * 4;
    int row0 = (bid >> 2) * 256;
    xs[threadIdx.x] = fully[row0 + threadIdx.x];
    __syncthreads();
    const float4* W = (const float4*)polW;
    size_t base = ((size_t)row0 * N_SUB + col) >> 2;
    float4 acc = make_float4(0.f, 0.f, 0.f, 0.f);
    #pragma unroll 4
    for (int i = 0; i < 256; i++) {
        float x = xs[i];
        float4 w = W[base + (size_t)i * (N_SUB / 4)];
        acc.x += x * w.x; acc.y += x * w.y; acc.z += x * w.z; acc.w += x * w.w;
    }
    atomicAdd(&logits[col + 0], acc.x);
    atomicAdd(&logits[col + 1], acc.y);
    atomicAdd(&logits[col + 2], acc.z);
    atomicAdd(&logits[col + 3], acc.w);
}

// single block, 1024 threads: softmax(logits + pol_b) -> out[0..4095]; out[4096] = value
__global__ __launch_bounds__(1024) void k_softmax(const float* __restrict__ lacc,
                                                  const float* __restrict__ polB,
                                                  const float* __restrict__ vacc,
                                                  const float* __restrict__ valB,
                                                  float* __restrict__ out) {
    __shared__ float smax[16], ssum[16], sbc[2];
    int t = threadIdx.x;
    float l[4];
    float m = -1e30f;
    #pragma unroll
    for (int k = 0; k < 4; k++) {
        int idx = t + (k << 10);
        l[k] = lacc[idx] + polB[idx];
        m = fmaxf(m, l[k]);
    }
    #pragma unroll
    for (int off = 32; off; off >>= 1) m = fmaxf(m, __shfl_down(m, off, 64));
    if ((t & 63) == 0) smax[t >> 6] = m;
    __syncthreads();
    if (t < 64) {
        float mm = (t < 16) ? smax[t] : -1e30f;
        #pragma unroll
        for (int off = 8; off; off >>= 1) mm = fmaxf(mm, __shfl_down(mm, off, 64));
        if (t == 0) sbc[0] = mm;
    }
    __syncthreads();
    m = sbc[0];
    float s = 0.0f;
    #pragma unroll
    for (int k = 0; k < 4; k++) { l[k] = expf(l[k] - m); s += l[k]; }
    #pragma unroll
    for (int off = 32; off; off >>= 1) s += __shfl_down(s, off, 64);
    if ((t & 63) == 0) ssum[t >> 6] = s;
    __syncthreads();
    if (t < 64) {
        float ss = (t < 16) ? ssum[t] : 0.0f;
        #pragma unroll
        for (int off = 8; off; off >>= 1) ss += __shfl_down(ss, off, 64);
        if (t == 0) sbc[1] = ss;
    }
    __syncthreads();
    float inv = 1.0f / sbc[1];
    #pragma unroll
    for (int k = 0; k < 4; k++) {
        int idx = t + (k << 10);
        out[idx] = l[k] * inv;
    }
    if (t == 0) out[N_SUB] = vacc[0] + valB[0];
}

extern "C" void kernel_launch(void* const* d_in, const int* in_sizes, int n_in,
                              void* d_out, int out_size, void* d_ws, size_t ws_size,
                              hipStream_t stream) {
    const float* subs_x = (const float*)d_in[0];
    const float* vnrx   = (const float*)d_in[1];
    const float* chebW  = (const float*)d_in[2];
    const float* chebB  = (const float*)d_in[3];
    const float* vnrW   = (const float*)d_in[4];
    const float* vnrB   = (const float*)d_in[5];
    const float* polW   = (const float*)d_in[6];
    const float* polB   = (const float*)d_in[7];
    const float* valW   = (const float*)d_in[8];
    const float* valB   = (const float*)d_in[9];
    const int*   ei     = (const int*)d_in[10];   // [2, N_EDGES]: src then dst
    const int*   perm   = (const int*)d_in[11];
    const int*   jp     = (const int*)d_in[12];
    float* ws  = (float*)d_ws;
    float* out = (float*)d_out;

    hipMemsetAsync(ws, 0, ZERO_FLOATS * sizeof(float), stream);
    k_deg<<<N_EDGES / 256, 256, 0, stream>>>(ei, ws + OFF_DEG);
    k_dinv<<<N_SUB / 256, 256, 0, stream>>>(ws + OFF_DEG);
    k_scatter<<<N_EDGES / 256, 256, 0, stream>>>(ei, ei + N_EDGES, ws + OFF_DEG,
                                                 subs_x, ws + OFF_TX1);
    k_scatter<<<N_EDGES / 256, 256, 0, stream>>>(ei, ei + N_EDGES, ws + OFF_DEG,
                                                 ws + OFF_TX1, ws + OFF_S2);
    k_conv<<<N_SUB / 256, 256, 0, stream>>>(subs_x, ws + OFF_TX1, ws + OFF_S2,
                                            chebW, chebB, vnrx, vnrW, vnrB, jp,
                                            ws + OFF_CONV, ws + OFF_VIRT);
    k_fully<<<N_FULLY / 256, 256, 0, stream>>>(perm, ws + OFF_CONV, ws + OFF_VIRT,
                                               valW, ws + OFF_FULLY, ws + OFF_VAL);
    k_logits<<<1024, 256, 0, stream>>>(ws + OFF_FULLY, polW, ws + OFF_LOG);
    k_softmax<<<1, 1024, 0, stream>>>(ws + OFF_LOG, polB, ws + OFF_VAL, valB, out);
}